// Round 9
// baseline (867.834 us; speedup 1.0000x reference)
//
#include <hip/hip_runtime.h>
#include <hip/hip_fp16.h>
#include <cstdint>
#include <cmath>

#define HID 96
#define INC 128
#define OUTC 40
#define ROWS 16

// ---------------- nontemporal helpers ----------------
typedef int      v4i __attribute__((ext_vector_type(4)));
typedef float    v4f __attribute__((ext_vector_type(4)));
typedef float    v2f __attribute__((ext_vector_type(2)));

__device__ __forceinline__ int4 ntld_i4(const int* p){
  v4i v = __builtin_nontemporal_load((const v4i*)p);
  return make_int4(v.x, v.y, v.z, v.w);
}
__device__ __forceinline__ float4 ntld_f4(const float* p){
  v4f v = __builtin_nontemporal_load((const v4f*)p);
  return make_float4(v.x, v.y, v.z, v.w);
}
__device__ __forceinline__ void ntst_u1(void* p, unsigned a){
  __builtin_nontemporal_store(a, (unsigned*)p);
}
__device__ __forceinline__ void ntst_f2(float* p, float a, float b){
  v2f v; v.x = a; v.y = b;
  __builtin_nontemporal_store(v, (v2f*)p);
}

// ---------------- threefry2x32 (JAX exact) ----------------
__device__ __forceinline__ unsigned rotl32d(unsigned x, int r){ return (x<<r)|(x>>(32-r)); }

__device__ __forceinline__ void tf2x32_dev(unsigned k0, unsigned k1, unsigned x0, unsigned x1,
                                           unsigned &y0, unsigned &y1){
  unsigned ks2 = k0 ^ k1 ^ 0x1BD11BDAu;
  x0 += k0; x1 += k1;
#define TFR(r) { x0 += x1; x1 = rotl32d(x1, r); x1 ^= x0; }
  TFR(13) TFR(15) TFR(26) TFR(6)   x0 += k1;  x1 += ks2 + 1u;
  TFR(17) TFR(29) TFR(16) TFR(24)  x0 += ks2; x1 += k0 + 2u;
  TFR(13) TFR(15) TFR(26) TFR(6)   x0 += k0;  x1 += k1 + 3u;
  TFR(17) TFR(29) TFR(16) TFR(24)  x0 += k1;  x1 += ks2 + 4u;
  TFR(13) TFR(15) TFR(26) TFR(6)   x0 += ks2; x1 += k0 + 5u;
#undef TFR
  y0 = x0; y1 = x1;
}

__device__ __forceinline__ unsigned tf_bits(unsigned k0, unsigned k1, unsigned idx){
  unsigned y0, y1; tf2x32_dev(k0, k1, 0u, idx, y0, y1); return y0 ^ y1;
}

__device__ __forceinline__ float u01_from_bits(unsigned bits){
  return __uint_as_float((bits >> 9) | 0x3f800000u) - 1.0f;
}

// XLA f32 ErfInv polynomial
__device__ __forceinline__ float erfinv_xla(float x){
  float w = -log1pf(-x*x);
  float p;
  if (w < 5.0f){
    w = w - 2.5f;
    p = 2.81022636e-08f;
    p = fmaf(p,w, 3.43273939e-07f);
    p = fmaf(p,w,-3.5233877e-06f);
    p = fmaf(p,w,-4.39150654e-06f);
    p = fmaf(p,w, 0.00021858087f);
    p = fmaf(p,w,-0.00125372503f);
    p = fmaf(p,w,-0.00417768164f);
    p = fmaf(p,w, 0.246640727f);
    p = fmaf(p,w, 1.50140941f);
  } else {
    w = sqrtf(w) - 3.0f;
    p = -0.000200214257f;
    p = fmaf(p,w, 0.000100950558f);
    p = fmaf(p,w, 0.00134934322f);
    p = fmaf(p,w,-0.00367342844f);
    p = fmaf(p,w, 0.00573950773f);
    p = fmaf(p,w,-0.0076224613f);
    p = fmaf(p,w, 0.00943887047f);
    p = fmaf(p,w, 1.00167406f);
    p = fmaf(p,w, 2.83297682f);
  }
  return p*x;
}

// ---------------- setup kernels ----------------
__global__ void k_detect(const unsigned* __restrict__ raw, int* flag){
  unsigned v = raw[2*threadIdx.x + 1];
  unsigned long long m = __ballot(v == 0u);
  if (threadIdx.x == 0) *flag = (m == 0xFFFFFFFFFFFFFFFFull) ? 1 : 0;
}

__global__ void k_convcount(const unsigned* __restrict__ raw, const int* __restrict__ flag,
                            int E, int* __restrict__ cnt){
  int e = blockIdx.x*256 + threadIdx.x; if (e >= E) return;
  int d;
  if (*flag) d = (int)raw[2*((size_t)E + e)];
  else       d = ((const int*)raw)[E + e];
  atomicAdd(&cnt[d], 1);
}

__global__ void k_hist(const int* __restrict__ cnt, int N, int* __restrict__ bcnt){
  __shared__ int lh[64];
  int tid = threadIdx.x; int n = blockIdx.x*256 + tid;
  if (tid < 64) lh[tid] = 0;
  __syncthreads();
  if (n < N) atomicAdd(&lh[min(cnt[n], 63)], 1);
  __syncthreads();
  if (tid < 64){
    int c = lh[tid];
    if (c > 0) atomicAdd(&bcnt[tid], c);
  }
}

__global__ void k_bucketoff(int* __restrict__ bcnt){
  __shared__ int sb[64];
  int tid = threadIdx.x;
  sb[tid] = bcnt[tid];
  __syncthreads();
  int off = 0;
  for (int b2 = tid+1; b2 < 64; b2++) off += sb[b2];
  bcnt[tid] = off;
}

__global__ void k_perm(const int* __restrict__ cnt, int N, int* __restrict__ boff,
                       int* __restrict__ perm, int* __restrict__ iperm,
                       float* __restrict__ diso, float* __restrict__ dsqr,
                       int* __restrict__ degv, int* __restrict__ degp){
  __shared__ int lh[64];
  int tid = threadIdx.x; int n = blockIdx.x*256 + tid;
  int v = (n < N) ? cnt[n] : 0;
  if (tid < 64) lh[tid] = 0;
  __syncthreads();
  int b = min(v, 63), r = 0;
  if (n < N) r = atomicAdd(&lh[b], 1);
  __syncthreads();
  if (tid < 64){
    int c = lh[tid];
    lh[tid] = (c > 0) ? atomicAdd(&boff[tid], c) : 0;
  }
  __syncthreads();
  if (n < N){
    int pos = lh[b] + r;
    perm[pos] = n;
    iperm[n] = pos;
    diso[n] = 1.0f / sqrtf((float)(v + 1));
    dsqr[pos] = 1.0f / (float)(v + 1);
    degv[pos] = v;
    degp[pos] = (v + 7) & ~7;
  }
}

__global__ void k_scanA(const int* __restrict__ degp, int N, int* __restrict__ psum){
  __shared__ int sh[256];
  int tid = threadIdx.x; int n = blockIdx.x*256 + tid;
  sh[tid] = (n < N) ? degp[n] : 0;
  for (int off = 128; off > 0; off >>= 1){
    __syncthreads();
    if (tid < off) sh[tid] += sh[tid + off];
  }
  __syncthreads();
  if (tid == 0) psum[blockIdx.x] = sh[0];
}

__global__ void k_scanB(int* __restrict__ psum, int nb){
  __shared__ int sh[256];
  int tid = threadIdx.x;
  int v = (tid < nb) ? psum[tid] : 0;
  sh[tid] = v;
  __syncthreads();
  for (int off = 1; off < 256; off <<= 1){
    int t = (tid >= off) ? sh[tid - off] : 0;
    __syncthreads();
    sh[tid] += t;
    __syncthreads();
  }
  if (tid < nb) psum[tid] = sh[tid] - v;   // exclusive
}

__global__ void k_rowptr2(const int* __restrict__ degv, const int* __restrict__ degp,
                          const int* __restrict__ psum, int N,
                          int* __restrict__ rowptr, int* __restrict__ csr_src,
                          float* __restrict__ csr_w){
  __shared__ int sh[256];
  int tid = threadIdx.x; int n = blockIdx.x*256 + tid;
  int vp = (n < N) ? degp[n] : 0;
  sh[tid] = vp;
  __syncthreads();
  for (int off = 1; off < 256; off <<= 1){
    int t = (tid >= off) ? sh[tid - off] : 0;
    __syncthreads();
    sh[tid] += t;
    __syncthreads();
  }
  if (n < N){
    int base = psum[blockIdx.x] + sh[tid] - vp;
    rowptr[n] = base;
    int v = degv[n];
    for (int q = v; q < vp; q++){ csr_src[base + q] = 0; csr_w[base + q] = 0.0f; }
    if (n == N-1) rowptr[N] = base + vp;
  }
}

__global__ void k_fill(const unsigned* __restrict__ raw, const int* __restrict__ flag, int E,
                       const int* __restrict__ rowptr, const int* __restrict__ iperm,
                       int* __restrict__ cur, const float* __restrict__ diso,
                       int* __restrict__ csr_src, float* __restrict__ csr_w){
  int e = blockIdx.x*256 + threadIdx.x; if (e >= E) return;
  int s, d;
  if (*flag){ s = (int)raw[2*(size_t)e]; d = (int)raw[2*((size_t)E + e)]; }
  else      { const int* r = (const int*)raw; s = r[e]; d = r[E + e]; }
  int rd = iperm[d];
  int pos = atomicAdd(&cur[rd], 1);
  int slot = rowptr[rd] + pos;
  csr_src[slot] = iperm[s];
  csr_w[slot] = diso[s]*diso[d];
}

// ---------------- h0 = x@proj_w + b, layer-0 quantization; outputs in PERM (r) order ----------------
__global__ __launch_bounds__(256) void k_h0(
  const float* __restrict__ x, const float* __restrict__ W, const float* __restrict__ bias,
  const int* __restrict__ iperm,
  float* __restrict__ h0p, __half* __restrict__ hq, unsigned kq0, unsigned kq1, int N)
{
  __shared__ float xs[64*65];
  __shared__ float wsh[64*96];
  int tid = threadIdx.x; int n0 = blockIdx.x*64;
  int cg = tid & 15, ng = tid >> 4; int c0 = cg*6;
  float acc[4][6];
#pragma unroll
  for (int i=0;i<4;i++) for (int j=0;j<6;j++) acc[i][j]=0.f;
  for (int kc=0; kc<2; kc++){
    if (kc) __syncthreads();
    for (int q=tid; q<1536; q+=256)
      ((float4*)wsh)[q] = ((const float4*)(W + kc*64*96))[q];
    for (int q=tid; q<1024; q+=256){
      int g=q*4; int r=g>>6, col=g&63;
      int n=n0+r; int ns = n<N ? n : N-1;
      float4 v = ((const float4*)(x + (size_t)ns*128 + kc*64))[col>>2];
      xs[r*65+col]=v.x; xs[r*65+col+1]=v.y; xs[r*65+col+2]=v.z; xs[r*65+col+3]=v.w;
    }
    __syncthreads();
    for (int k=0;k<64;k++){
      float wv[6];
#pragma unroll
      for (int j=0;j<6;j++) wv[j]=wsh[k*96 + c0 + j];
#pragma unroll
      for (int i=0;i<4;i++){
        float xv = xs[(ng*4+i)*65 + k];
#pragma unroll
        for (int j=0;j<6;j++) acc[i][j] = fmaf(xv, wv[j], acc[i][j]);
      }
    }
  }
#pragma unroll
  for (int i=0;i<4;i++){
    int n = n0 + ng*4 + i; if (n >= N) continue;
    int rn = iperm[n];
#pragma unroll
    for (int j=0;j<6;j++){
      int c = c0 + j; int p = n*96 + c;      // RNG index uses ORIGINAL id
      float v = acc[i][j] + bias[c];
      h0p[(size_t)rn*96 + c] = v;
      unsigned bq = tf_bits(kq0, kq1, (unsigned)p);
      float b = u01_from_bits(bq) - 0.5f;     // delta = 1
      hq[(size_t)rn*96 + c] = __float2half_rn(floorf(v + b) - b);
    }
  }
}

// ---------------- fused per-layer kernel ----------------
// ROWS=16, hoisted RNG (13 pinned VGPRs, no spill at VGPR=64 -- round 8).
// waves_per_eu(4,8): round 8's (4,4) capped residency at 4 waves/EU (occupancy 36%)
// while VGPR=64 + LDS 15.9K permit 8. Min 4 keeps the same register budget.
#define GATH(gj, wv) { \
  float2 f01 = __half22float2(*(__half2*)&gj.x); \
  float2 f23 = __half22float2(*(__half2*)&gj.y); \
  ax = fmaf(f01.x, wv, ax); ay = fmaf(f01.y, wv, ay); \
  az = fmaf(f23.x, wv, az); aw = fmaf(f23.y, wv, aw); }

__global__ __launch_bounds__(256) __attribute__((amdgpu_waves_per_eu(4,8)))
void k_layer(
  const __half* __restrict__ hq_in, const float* __restrict__ h0p, const float* __restrict__ dsqr,
  const int* __restrict__ rowptr, const int* __restrict__ csr_src, const float* __restrict__ csr_w,
  const int* __restrict__ perm, const float* __restrict__ W,
  float betaf, float ombf,
  unsigned ke0, unsigned ke1, unsigned kd0, unsigned kd1,
  unsigned kq0, unsigned kq1, float delta_n, float invdelta_n,
  int do_dropout, int write_h,
  __half* __restrict__ hq_out, float* __restrict__ h_out, int N)
{
  __shared__ float ts[ROWS*100];   // 6400 B t tile, stride 100
  __shared__ float wsh[24*96];     // 9216 B W K-chunk
  int tid = threadIdx.x;
  int tx = tid & 31, ty = tid >> 5;    // 8 rows in flight in gather
  int n0 = blockIdx.x*ROWS;
  int cg = tid & 15, ng = tid >> 4;    // epilogue: row ng (0..15), cols c0..c0+5
  int c0 = cg * 6;
  int n = n0 + ng;

  // ---- phase 0: hoisted RNG (overlaps gather latency via wave interleave) ----
  const float LO = __uint_as_float(0xBF7FFFFFu);   // nextafter(-1,0)
  float noise[6], qb[6];
  unsigned dmask = 0;
#pragma unroll
  for (int j = 0; j < 6; j++){ noise[j] = 0.f; qb[j] = 0.f; }
  if (n < N){
    unsigned pb = (unsigned)perm[n]*96u + (unsigned)c0;   // ORIGINAL id for RNG stream
#pragma unroll
    for (int j = 0; j < 6; j++){
      unsigned p = pb + (unsigned)j;
      unsigned be = tf_bits(ke0, ke1, p);
      float uv = fmaxf(LO, u01_from_bits(be)*2.0f + LO);
      noise[j] = 0.01f * (1.41421356f * erfinv_xla(uv));
      if (do_dropout){
        unsigned bd = tf_bits(kd0, kd1, p);
        if (bd < 0x80000000u) dmask |= (1u << j);
      }
      if (!write_h){
        unsigned bq = tf_bits(kq0, kq1, p);
        qb[j] = (u01_from_bits(bq) - 0.5f)*delta_n;
      }
    }
  }
  // pin: forbid the compiler from sinking the RNG below the gather
  asm volatile("" :
    "+v"(noise[0]),"+v"(noise[1]),"+v"(noise[2]),"+v"(noise[3]),
    "+v"(noise[4]),"+v"(noise[5]),
    "+v"(qb[0]),"+v"(qb[1]),"+v"(qb[2]),"+v"(qb[3]),
    "+v"(qb[4]),"+v"(qb[5]),
    "+v"(dmask));

  const char* hqc = (const char*)hq_in;

  // ---- phase 1: gather 16 rows, 2 passes of 8 concurrent rows ----
#pragma unroll 1
  for (int pass = 0; pass < 2; pass++){
    int r = pass*8 + ty;
    int row = n0 + r;
    if (tx < 24){
      float4 o = make_float4(0.f, 0.f, 0.f, 0.f);
      if (row < N){
        unsigned txb = (unsigned)tx*8u;
        float dd = dsqr[row];
        unsigned lo = (unsigned)rowptr[row], hi = (unsigned)rowptr[row+1];
        uint2 sraw = *(const uint2*)(hqc + (unsigned)row*192u + txb);
        float4 hz = ntld_f4(h0p + (size_t)row*96 + tx*4);
        float2 s01 = __half22float2(*(__half2*)&sraw.x);
        float2 s23 = __half22float2(*(__half2*)&sraw.y);
        float ax = s01.x*dd, ay = s01.y*dd, az = s23.x*dd, aw = s23.y*dd;
        unsigned s = lo;
        unsigned n16 = lo + ((hi - lo) & ~15u);
        for (; s < n16; s += 16){
          int4   sa = ntld_i4(csr_src + s);
          int4   sb = ntld_i4(csr_src + s + 4);
          int4   sc = ntld_i4(csr_src + s + 8);
          int4   sd = ntld_i4(csr_src + s + 12);
          float4 wa = ntld_f4(csr_w + s);
          float4 wb = ntld_f4(csr_w + s + 4);
          float4 wc = ntld_f4(csr_w + s + 8);
          float4 wd = ntld_f4(csr_w + s + 12);
          uint2 g0 = *(const uint2*)(hqc + (unsigned)sa.x*192u + txb);
          uint2 g1 = *(const uint2*)(hqc + (unsigned)sa.y*192u + txb);
          uint2 g2 = *(const uint2*)(hqc + (unsigned)sa.z*192u + txb);
          uint2 g3 = *(const uint2*)(hqc + (unsigned)sa.w*192u + txb);
          uint2 g4 = *(const uint2*)(hqc + (unsigned)sb.x*192u + txb);
          uint2 g5 = *(const uint2*)(hqc + (unsigned)sb.y*192u + txb);
          uint2 g6 = *(const uint2*)(hqc + (unsigned)sb.z*192u + txb);
          uint2 g7 = *(const uint2*)(hqc + (unsigned)sb.w*192u + txb);
          uint2 g8 = *(const uint2*)(hqc + (unsigned)sc.x*192u + txb);
          uint2 g9 = *(const uint2*)(hqc + (unsigned)sc.y*192u + txb);
          uint2 gA = *(const uint2*)(hqc + (unsigned)sc.z*192u + txb);
          uint2 gB = *(const uint2*)(hqc + (unsigned)sc.w*192u + txb);
          uint2 gC = *(const uint2*)(hqc + (unsigned)sd.x*192u + txb);
          uint2 gD = *(const uint2*)(hqc + (unsigned)sd.y*192u + txb);
          uint2 gE = *(const uint2*)(hqc + (unsigned)sd.z*192u + txb);
          uint2 gF = *(const uint2*)(hqc + (unsigned)sd.w*192u + txb);
          GATH(g0, wa.x) GATH(g1, wa.y) GATH(g2, wa.z) GATH(g3, wa.w)
          GATH(g4, wb.x) GATH(g5, wb.y) GATH(g6, wb.z) GATH(g7, wb.w)
          GATH(g8, wc.x) GATH(g9, wc.y) GATH(gA, wc.z) GATH(gB, wc.w)
          GATH(gC, wd.x) GATH(gD, wd.y) GATH(gE, wd.z) GATH(gF, wd.w)
        }
        for (; s < hi; s += 8){
          int4   sa = ntld_i4(csr_src + s);
          int4   sb = ntld_i4(csr_src + s + 4);
          float4 wa = ntld_f4(csr_w + s);
          float4 wb = ntld_f4(csr_w + s + 4);
          uint2 g0 = *(const uint2*)(hqc + (unsigned)sa.x*192u + txb);
          uint2 g1 = *(const uint2*)(hqc + (unsigned)sa.y*192u + txb);
          uint2 g2 = *(const uint2*)(hqc + (unsigned)sa.z*192u + txb);
          uint2 g3 = *(const uint2*)(hqc + (unsigned)sa.w*192u + txb);
          uint2 g4 = *(const uint2*)(hqc + (unsigned)sb.x*192u + txb);
          uint2 g5 = *(const uint2*)(hqc + (unsigned)sb.y*192u + txb);
          uint2 g6 = *(const uint2*)(hqc + (unsigned)sb.z*192u + txb);
          uint2 g7 = *(const uint2*)(hqc + (unsigned)sb.w*192u + txb);
          GATH(g0, wa.x) GATH(g1, wa.y) GATH(g2, wa.z) GATH(g3, wa.w)
          GATH(g4, wb.x) GATH(g5, wb.y) GATH(g6, wb.z) GATH(g7, wb.w)
        }
        o.x = 0.9f*ax + 0.1f*hz.x;
        o.y = 0.9f*ay + 0.1f*hz.y;
        o.z = 0.9f*az + 0.1f*hz.z;
        o.w = 0.9f*aw + 0.1f*hz.w;
      }
      *((float4*)&ts[r*100 + tx*4]) = o;
    }
  }

  // ---- phase 2: matmul (1 row x 6 ch per thread) ----
  float acc[6];
#pragma unroll
  for (int j = 0; j < 6; j++) acc[j] = 0.f;

  for (int chunk = 0; chunk < 4; chunk++){
    __syncthreads();
    for (int q = tid; q < 576; q += 256)
      ((float4*)wsh)[q] = ((const float4*)(W + chunk*24*96))[q];
    __syncthreads();
#pragma unroll 4
    for (int kk = 0; kk < 24; kk++){
      int k = chunk*24 + kk;
      float2 w0 = *((const float2*)&wsh[kk*96 + c0]);
      float2 w1 = *((const float2*)&wsh[kk*96 + c0 + 2]);
      float2 w2 = *((const float2*)&wsh[kk*96 + c0 + 4]);
      float xv = ts[ng*100 + k];
      acc[0] = fmaf(xv, w0.x, acc[0]);  acc[1] = fmaf(xv, w0.y, acc[1]);
      acc[2] = fmaf(xv, w1.x, acc[2]);  acc[3] = fmaf(xv, w1.y, acc[3]);
      acc[4] = fmaf(xv, w2.x, acc[4]);  acc[5] = fmaf(xv, w2.y, acc[5]);
    }
  }

  // ---- light epilogue (RNG already in registers) ----
  if (n < N){
    float res[6];
#pragma unroll
    for (int j = 0; j < 6; j++){
      int c = c0 + j;
      float tv = ts[ng*100 + c];
      float hv = ombf*tv + betaf*acc[j];
      hv += noise[j];
      hv = fmaxf(hv, 0.0f);
      if (do_dropout)
        hv = (dmask & (1u << j)) ? hv*2.0f : 0.0f;
      if (!write_h)
        hv = floorf((hv + qb[j])*invdelta_n)*delta_n - qb[j];
      res[j] = hv;
    }
    if (write_h){
      float* dst2 = h_out + (size_t)n*96 + c0;
      ntst_f2(&dst2[0], res[0], res[1]);
      ntst_f2(&dst2[2], res[2], res[3]);
      ntst_f2(&dst2[4], res[4], res[5]);
    } else {
      __half* dst2 = hq_out + (size_t)n*96 + c0;
#pragma unroll
      for (int j2 = 0; j2 < 3; j2++){
        unsigned pk = (unsigned)__half_as_ushort(__float2half_rn(res[j2*2+0]))
                    | ((unsigned)__half_as_ushort(__float2half_rn(res[j2*2+1])) << 16);
        ntst_u1(dst2 + j2*2, pk);
      }
    }
  }
}

// ---------------- out = [h0, h] @ out_w + out_b (inputs r-order, output scattered) ----------------
__global__ __launch_bounds__(256) void k_final(
  const float* __restrict__ h0p, const float* __restrict__ hp,
  const float* __restrict__ W, const float* __restrict__ bias,
  const int* __restrict__ perm, float* __restrict__ out, int N)
{
  __shared__ float xs[64*97];
  __shared__ float wsh[96*40];
  int tid = threadIdx.x; int n0 = blockIdx.x*64;
  int cg = tid & 7, ng = tid >> 3; int c0 = cg*5;
  float acc[2][5];
#pragma unroll
  for (int i=0;i<2;i++) for (int j=0;j<5;j++) acc[i][j]=0.f;
  for (int ph=0; ph<2; ph++){
    if (ph) __syncthreads();
    const float* xsrc = ph ? hp : h0p;
    for (int q=tid; q<960; q+=256)
      ((float4*)wsh)[q] = ((const float4*)(W + ph*96*40))[q];
    for (int q=tid; q<1536; q+=256){
      int g=q*4; int r=g/96, col=g%96;
      int n=n0+r; int ns = n<N ? n : N-1;
      float4 v = ((const float4*)(xsrc + (size_t)ns*96))[col>>2];
      xs[r*97+col]=v.x; xs[r*97+col+1]=v.y; xs[r*97+col+2]=v.z; xs[r*97+col+3]=v.w;
    }
    __syncthreads();
    for (int k=0;k<96;k++){
      float wv[5];
#pragma unroll
      for (int j=0;j<5;j++) wv[j]=wsh[k*40 + c0 + j];
#pragma unroll
      for (int i=0;i<2;i++){
        float xv = xs[(ng*2+i)*97 + k];
#pragma unroll
        for (int j=0;j<5;j++) acc[i][j] = fmaf(xv, wv[j], acc[i][j]);
      }
    }
  }
#pragma unroll
  for (int i=0;i<2;i++){
    int n = n0 + ng*2 + i; if (n >= N) continue;
    int pm = perm[n];
#pragma unroll
    for (int j=0;j<5;j++)
      out[(size_t)pm*40 + c0 + j] = acc[i][j] + bias[c0 + j];
  }
}

// ---------------- host ----------------
static void tf_host(uint32_t k0, uint32_t k1, uint32_t x0, uint32_t x1,
                    uint32_t &y0, uint32_t &y1){
  uint32_t ks2 = k0 ^ k1 ^ 0x1BD11BDAu;
  x0 += k0; x1 += k1;
  auto R = [&](int r){ x0 += x1; x1 = (x1<<r)|(x1>>(32-r)); x1 ^= x0; };
  R(13);R(15);R(26);R(6);   x0 += k1;  x1 += ks2 + 1u;
  R(17);R(29);R(16);R(24);  x0 += ks2; x1 += k0 + 2u;
  R(13);R(15);R(26);R(6);   x0 += k0;  x1 += k1 + 3u;
  R(17);R(29);R(16);R(24);  x0 += k1;  x1 += ks2 + 4u;
  R(13);R(15);R(26);R(6);   x0 += ks2; x1 += k0 + 5u;
  y0 = x0; y1 = x1;
}

extern "C" void kernel_launch(void* const* d_in, const int* in_sizes, int n_in,
                              void* d_out, int out_size, void* d_ws, size_t ws_size,
                              hipStream_t stream)
{
  const float*    x       = (const float*)d_in[0];
  const unsigned* eraw    = (const unsigned*)d_in[1];
  const float*    proj_w  = (const float*)d_in[2];
  const float*    proj_b  = (const float*)d_in[3];
  const float*    conv_w  = (const float*)d_in[4];
  const float*    out_w   = (const float*)d_in[5];
  const float*    out_b   = (const float*)d_in[6];
  float* out = (float*)d_out;

  const int N = in_sizes[0] / INC;     // 50000
  const int E = in_sizes[1] / 2;       // 800000
  const size_t NH = (size_t)N * HID;
  const int NP = (N + 16) & ~15;
  const int EP = ((E + 7*N + 15) & ~15);   // padded-CSR capacity (rows padded to x8)

  float*  ws     = (float*)d_ws;
  float*  h0p    = ws;                       // NH f32 (perm order)
  float*  hbp    = h0p + NH;                 // NH f32, last-layer h (perm order)
  __half* hqA    = (__half*)(hbp + NH);      // NH fp16 (ping, perm order)
  __half* hqB    = hqA + NH;                 // NH fp16 (pong)
  float*  csr_w  = (float*)(hqB + NH);       // EP f32
  int*    csr_src= (int*)(csr_w + EP);       // EP int
  int*    rowptr = csr_src + EP;             // NP (+1 used)
  int*    perm   = rowptr + NP;
  int*    iperm  = perm + NP;
  int*    degv   = iperm + NP;
  int*    degp   = degv + NP;
  int*    cnt    = degp + NP;
  int*    cur    = cnt + NP;
  float*  diso   = (float*)(cur + NP);
  float*  dsqr   = diso + NP;
  int*    bcnt   = (int*)(dsqr + NP);
  int*    psum   = bcnt + 64;
  int*    flag   = psum + 256;
  (void)ws_size; (void)n_in; (void)out_size;

  // JAX key chain: key(42) -> per layer split(key,4)
  uint32_t kq[8][2], ke[8][2], kd[8][2];
  {
    uint32_t K0 = 0u, K1 = 42u;
    for (int k = 0; k < 8; k++){
      uint32_t y0, y1;
      tf_host(K0, K1, 0u, 0u, y0, y1); kq[k][0]=y0; kq[k][1]=y1;
      tf_host(K0, K1, 0u, 1u, y0, y1); ke[k][0]=y0; ke[k][1]=y1;
      tf_host(K0, K1, 0u, 2u, y0, y1); kd[k][0]=y0; kd[k][1]=y1;
      tf_host(K0, K1, 0u, 3u, y0, y1); K0=y0; K1=y1;
    }
  }

  const int gE  = (E + 255)/256;
  const int gN  = (N + 255)/256;
  const int gMM = (N + 63)/64;
  const int gL  = (N + ROWS-1)/ROWS;

  hipMemsetAsync(cnt, 0, (size_t)N*4, stream);
  hipMemsetAsync(bcnt, 0, 64*4, stream);
  k_detect   <<<1, 64, 0, stream>>>(eraw, flag);
  k_convcount<<<gE, 256, 0, stream>>>(eraw, flag, E, cnt);
  k_hist     <<<gN, 256, 0, stream>>>(cnt, N, bcnt);
  k_bucketoff<<<1, 64, 0, stream>>>(bcnt);
  k_perm     <<<gN, 256, 0, stream>>>(cnt, N, bcnt, perm, iperm, diso, dsqr, degv, degp);
  k_scanA    <<<gN, 256, 0, stream>>>(degp, N, psum);
  k_scanB    <<<1, 256, 0, stream>>>(psum, gN);
  k_rowptr2  <<<gN, 256, 0, stream>>>(degv, degp, psum, N, rowptr, csr_src, csr_w);
  hipMemsetAsync(cur, 0, (size_t)N*4, stream);
  k_fill     <<<gE, 256, 0, stream>>>(eraw, flag, E, rowptr, iperm, cur, diso, csr_src, csr_w);

  k_h0<<<gMM, 256, 0, stream>>>(x, proj_w, proj_b, iperm, h0p, hqA, kq[0][0], kq[0][1], N);

  for (int k = 0; k < 8; k++){
    double bd = log(0.5/(double)(k+1) + 1.0);
    float betaf = (float)bd;
    float ombf  = (float)(1.0 - bd);
    int last = (k == 7);
    float dn  = 1.0f/(float)(1 << (k+1));
    float idn = (float)(1 << (k+1));
    const __half* hin  = (k & 1) ? hqB : hqA;   // ping-pong: no read/write race
    __half*       hout = (k & 1) ? hqA : hqB;
    k_layer<<<gL, 256, 0, stream>>>(hin, h0p, dsqr, rowptr, csr_src, csr_w, perm,
      conv_w + (size_t)k*HID*HID, betaf, ombf,
      ke[k][0], ke[k][1], kd[k][0], kd[k][1],
      last?0u:kq[k+1][0], last?0u:kq[k+1][1], dn, idn,
      !last, last, hout, hbp, N);
  }

  k_final<<<gMM, 256, 0, stream>>>(h0p, hbp, out_w, out_b, perm, out, N);
}

// Round 10
// 841.862 us; speedup vs baseline: 1.0309x; 1.0309x over previous
//
#include <hip/hip_runtime.h>
#include <hip/hip_fp16.h>
#include <cstdint>
#include <cmath>

#define HID 96
#define INC 128
#define OUTC 40
#define ROWS 16

// ---------------- nontemporal helpers ----------------
typedef int      v4i __attribute__((ext_vector_type(4)));
typedef float    v4f __attribute__((ext_vector_type(4)));
typedef float    v2f __attribute__((ext_vector_type(2)));

__device__ __forceinline__ int4 ntld_i4(const int* p){
  v4i v = __builtin_nontemporal_load((const v4i*)p);
  return make_int4(v.x, v.y, v.z, v.w);
}
__device__ __forceinline__ float4 ntld_f4(const float* p){
  v4f v = __builtin_nontemporal_load((const v4f*)p);
  return make_float4(v.x, v.y, v.z, v.w);
}
__device__ __forceinline__ void ntst_u1(void* p, unsigned a){
  __builtin_nontemporal_store(a, (unsigned*)p);
}
__device__ __forceinline__ void ntst_f2(float* p, float a, float b){
  v2f v; v.x = a; v.y = b;
  __builtin_nontemporal_store(v, (v2f*)p);
}

// ---------------- threefry2x32 (JAX exact) ----------------
__device__ __forceinline__ unsigned rotl32d(unsigned x, int r){ return (x<<r)|(x>>(32-r)); }

__device__ __forceinline__ void tf2x32_dev(unsigned k0, unsigned k1, unsigned x0, unsigned x1,
                                           unsigned &y0, unsigned &y1){
  unsigned ks2 = k0 ^ k1 ^ 0x1BD11BDAu;
  x0 += k0; x1 += k1;
#define TFR(r) { x0 += x1; x1 = rotl32d(x1, r); x1 ^= x0; }
  TFR(13) TFR(15) TFR(26) TFR(6)   x0 += k1;  x1 += ks2 + 1u;
  TFR(17) TFR(29) TFR(16) TFR(24)  x0 += ks2; x1 += k0 + 2u;
  TFR(13) TFR(15) TFR(26) TFR(6)   x0 += k0;  x1 += k1 + 3u;
  TFR(17) TFR(29) TFR(16) TFR(24)  x0 += k1;  x1 += ks2 + 4u;
  TFR(13) TFR(15) TFR(26) TFR(6)   x0 += ks2; x1 += k0 + 5u;
#undef TFR
  y0 = x0; y1 = x1;
}

__device__ __forceinline__ unsigned tf_bits(unsigned k0, unsigned k1, unsigned idx){
  unsigned y0, y1; tf2x32_dev(k0, k1, 0u, idx, y0, y1); return y0 ^ y1;
}

__device__ __forceinline__ float u01_from_bits(unsigned bits){
  return __uint_as_float((bits >> 9) | 0x3f800000u) - 1.0f;
}

// XLA f32 ErfInv polynomial
__device__ __forceinline__ float erfinv_xla(float x){
  float w = -log1pf(-x*x);
  float p;
  if (w < 5.0f){
    w = w - 2.5f;
    p = 2.81022636e-08f;
    p = fmaf(p,w, 3.43273939e-07f);
    p = fmaf(p,w,-3.5233877e-06f);
    p = fmaf(p,w,-4.39150654e-06f);
    p = fmaf(p,w, 0.00021858087f);
    p = fmaf(p,w,-0.00125372503f);
    p = fmaf(p,w,-0.00417768164f);
    p = fmaf(p,w, 0.246640727f);
    p = fmaf(p,w, 1.50140941f);
  } else {
    w = sqrtf(w) - 3.0f;
    p = -0.000200214257f;
    p = fmaf(p,w, 0.000100950558f);
    p = fmaf(p,w, 0.00134934322f);
    p = fmaf(p,w,-0.00367342844f);
    p = fmaf(p,w, 0.00573950773f);
    p = fmaf(p,w,-0.0076224613f);
    p = fmaf(p,w, 0.00943887047f);
    p = fmaf(p,w, 1.00167406f);
    p = fmaf(p,w, 2.83297682f);
  }
  return p*x;
}

// ---------------- setup kernels ----------------
__global__ void k_detect(const unsigned* __restrict__ raw, int* flag){
  unsigned v = raw[2*threadIdx.x + 1];
  unsigned long long m = __ballot(v == 0u);
  if (threadIdx.x == 0) *flag = (m == 0xFFFFFFFFFFFFFFFFull) ? 1 : 0;
}

__global__ void k_convcount(const unsigned* __restrict__ raw, const int* __restrict__ flag,
                            int E, int* __restrict__ cnt){
  int e = blockIdx.x*256 + threadIdx.x; if (e >= E) return;
  int d;
  if (*flag) d = (int)raw[2*((size_t)E + e)];
  else       d = ((const int*)raw)[E + e];
  atomicAdd(&cnt[d], 1);
}

__global__ void k_hist(const int* __restrict__ cnt, int N, int* __restrict__ bcnt){
  __shared__ int lh[64];
  int tid = threadIdx.x; int n = blockIdx.x*256 + tid;
  if (tid < 64) lh[tid] = 0;
  __syncthreads();
  if (n < N) atomicAdd(&lh[min(cnt[n], 63)], 1);
  __syncthreads();
  if (tid < 64){
    int c = lh[tid];
    if (c > 0) atomicAdd(&bcnt[tid], c);
  }
}

__global__ void k_bucketoff(int* __restrict__ bcnt){
  __shared__ int sb[64];
  int tid = threadIdx.x;
  sb[tid] = bcnt[tid];
  __syncthreads();
  int off = 0;
  for (int b2 = tid+1; b2 < 64; b2++) off += sb[b2];
  bcnt[tid] = off;
}

__global__ void k_perm(const int* __restrict__ cnt, int N, int* __restrict__ boff,
                       int* __restrict__ perm, int* __restrict__ iperm,
                       float* __restrict__ diso, float* __restrict__ dsqr,
                       int* __restrict__ degv, int* __restrict__ degp){
  __shared__ int lh[64];
  int tid = threadIdx.x; int n = blockIdx.x*256 + tid;
  int v = (n < N) ? cnt[n] : 0;
  if (tid < 64) lh[tid] = 0;
  __syncthreads();
  int b = min(v, 63), r = 0;
  if (n < N) r = atomicAdd(&lh[b], 1);
  __syncthreads();
  if (tid < 64){
    int c = lh[tid];
    lh[tid] = (c > 0) ? atomicAdd(&boff[tid], c) : 0;
  }
  __syncthreads();
  if (n < N){
    int pos = lh[b] + r;
    perm[pos] = n;
    iperm[n] = pos;
    diso[n] = 1.0f / sqrtf((float)(v + 1));
    dsqr[pos] = 1.0f / (float)(v + 1);
    degv[pos] = v;
    degp[pos] = (v + 7) & ~7;
  }
}

__global__ void k_scanA(const int* __restrict__ degp, int N, int* __restrict__ psum){
  __shared__ int sh[256];
  int tid = threadIdx.x; int n = blockIdx.x*256 + tid;
  sh[tid] = (n < N) ? degp[n] : 0;
  for (int off = 128; off > 0; off >>= 1){
    __syncthreads();
    if (tid < off) sh[tid] += sh[tid + off];
  }
  __syncthreads();
  if (tid == 0) psum[blockIdx.x] = sh[0];
}

__global__ void k_scanB(int* __restrict__ psum, int nb){
  __shared__ int sh[256];
  int tid = threadIdx.x;
  int v = (tid < nb) ? psum[tid] : 0;
  sh[tid] = v;
  __syncthreads();
  for (int off = 1; off < 256; off <<= 1){
    int t = (tid >= off) ? sh[tid - off] : 0;
    __syncthreads();
    sh[tid] += t;
    __syncthreads();
  }
  if (tid < nb) psum[tid] = sh[tid] - v;   // exclusive
}

__global__ void k_rowptr2(const int* __restrict__ degv, const int* __restrict__ degp,
                          const int* __restrict__ psum, int N,
                          int* __restrict__ rowptr, int* __restrict__ csr_src,
                          float* __restrict__ csr_w){
  __shared__ int sh[256];
  int tid = threadIdx.x; int n = blockIdx.x*256 + tid;
  int vp = (n < N) ? degp[n] : 0;
  sh[tid] = vp;
  __syncthreads();
  for (int off = 1; off < 256; off <<= 1){
    int t = (tid >= off) ? sh[tid - off] : 0;
    __syncthreads();
    sh[tid] += t;
    __syncthreads();
  }
  if (n < N){
    int base = psum[blockIdx.x] + sh[tid] - vp;
    rowptr[n] = base;
    int v = degv[n];
    for (int q = v; q < vp; q++){ csr_src[base + q] = 0; csr_w[base + q] = 0.0f; }
    if (n == N-1) rowptr[N] = base + vp;
  }
}

__global__ void k_fill(const unsigned* __restrict__ raw, const int* __restrict__ flag, int E,
                       const int* __restrict__ rowptr, const int* __restrict__ iperm,
                       int* __restrict__ cur, const float* __restrict__ diso,
                       int* __restrict__ csr_src, float* __restrict__ csr_w){
  int e = blockIdx.x*256 + threadIdx.x; if (e >= E) return;
  int s, d;
  if (*flag){ s = (int)raw[2*(size_t)e]; d = (int)raw[2*((size_t)E + e)]; }
  else      { const int* r = (const int*)raw; s = r[e]; d = r[E + e]; }
  int rd = iperm[d];
  int pos = atomicAdd(&cur[rd], 1);
  int slot = rowptr[rd] + pos;
  csr_src[slot] = iperm[s];
  csr_w[slot] = diso[s]*diso[d];
}

// ---------------- h0 = x@proj_w + b, layer-0 quantization; outputs in PERM (r) order ----------------
__global__ __launch_bounds__(256) void k_h0(
  const float* __restrict__ x, const float* __restrict__ W, const float* __restrict__ bias,
  const int* __restrict__ iperm,
  float* __restrict__ h0p, __half* __restrict__ hq, unsigned kq0, unsigned kq1, int N)
{
  __shared__ float xs[64*65];
  __shared__ float wsh[64*96];
  int tid = threadIdx.x; int n0 = blockIdx.x*64;
  int cg = tid & 15, ng = tid >> 4; int c0 = cg*6;
  float acc[4][6];
#pragma unroll
  for (int i=0;i<4;i++) for (int j=0;j<6;j++) acc[i][j]=0.f;
  for (int kc=0; kc<2; kc++){
    if (kc) __syncthreads();
    for (int q=tid; q<1536; q+=256)
      ((float4*)wsh)[q] = ((const float4*)(W + kc*64*96))[q];
    for (int q=tid; q<1024; q+=256){
      int g=q*4; int r=g>>6, col=g&63;
      int n=n0+r; int ns = n<N ? n : N-1;
      float4 v = ((const float4*)(x + (size_t)ns*128 + kc*64))[col>>2];
      xs[r*65+col]=v.x; xs[r*65+col+1]=v.y; xs[r*65+col+2]=v.z; xs[r*65+col+3]=v.w;
    }
    __syncthreads();
    for (int k=0;k<64;k++){
      float wv[6];
#pragma unroll
      for (int j=0;j<6;j++) wv[j]=wsh[k*96 + c0 + j];
#pragma unroll
      for (int i=0;i<4;i++){
        float xv = xs[(ng*4+i)*65 + k];
#pragma unroll
        for (int j=0;j<6;j++) acc[i][j] = fmaf(xv, wv[j], acc[i][j]);
      }
    }
  }
#pragma unroll
  for (int i=0;i<4;i++){
    int n = n0 + ng*4 + i; if (n >= N) continue;
    int rn = iperm[n];
#pragma unroll
    for (int j=0;j<6;j++){
      int c = c0 + j; int p = n*96 + c;      // RNG index uses ORIGINAL id
      float v = acc[i][j] + bias[c];
      h0p[(size_t)rn*96 + c] = v;
      unsigned bq = tf_bits(kq0, kq1, (unsigned)p);
      float b = u01_from_bits(bq) - 0.5f;     // delta = 1
      hq[(size_t)rn*96 + c] = __float2half_rn(floorf(v + b) - b);
    }
  }
}

// ---------------- fused per-layer kernel ----------------
// ROWS=16, hoisted RNG (13 pinned VGPRs, no spill -- round 8 counters clean).
// NEW: whole W (96x96, 36.8KB) staged to LDS ONCE, loads issued BEFORE the RNG phase
// (HBM/L2 latency hides under ~1.6K VALU instrs), and the matmul runs the full K=96
// loop with a SINGLE barrier in the kernel (was 1+8 barriers with 4 W-chunks).
// LDS 43.3KB -> 3 blocks/CU, which equals the residency we measure anyway.
#define GATH(gj, wv) { \
  float2 f01 = __half22float2(*(__half2*)&gj.x); \
  float2 f23 = __half22float2(*(__half2*)&gj.y); \
  ax = fmaf(f01.x, wv, ax); ay = fmaf(f01.y, wv, ay); \
  az = fmaf(f23.x, wv, az); aw = fmaf(f23.y, wv, aw); }

__global__ __launch_bounds__(256) __attribute__((amdgpu_waves_per_eu(4,4)))
void k_layer(
  const __half* __restrict__ hq_in, const float* __restrict__ h0p, const float* __restrict__ dsqr,
  const int* __restrict__ rowptr, const int* __restrict__ csr_src, const float* __restrict__ csr_w,
  const int* __restrict__ perm, const float* __restrict__ W,
  float betaf, float ombf,
  unsigned ke0, unsigned ke1, unsigned kd0, unsigned kd1,
  unsigned kq0, unsigned kq1, float delta_n, float invdelta_n,
  int do_dropout, int write_h,
  __half* __restrict__ hq_out, float* __restrict__ h_out, int N)
{
  __shared__ float ts[ROWS*100];   // 6400 B t tile, stride 100
  __shared__ float wsh[96*96];     // 36864 B: the WHOLE W
  int tid = threadIdx.x;
  int tx = tid & 31, ty = tid >> 5;    // 8 rows in flight in gather
  int n0 = blockIdx.x*ROWS;
  int cg = tid & 15, ng = tid >> 4;    // epilogue: row ng (0..15), cols c0..c0+5
  int c0 = cg * 6;
  int n = n0 + ng;

  // ---- phase -1: issue full-W staging; latency hides under the RNG phase ----
#pragma unroll
  for (int q = 0; q < 9; q++)
    ((float4*)wsh)[tid + q*256] = ((const float4*)W)[tid + q*256];

  // ---- phase 0: hoisted RNG (overlaps W-load + gather latency) ----
  const float LO = __uint_as_float(0xBF7FFFFFu);   // nextafter(-1,0)
  float noise[6], qb[6];
  unsigned dmask = 0;
#pragma unroll
  for (int j = 0; j < 6; j++){ noise[j] = 0.f; qb[j] = 0.f; }
  if (n < N){
    unsigned pb = (unsigned)perm[n]*96u + (unsigned)c0;   // ORIGINAL id for RNG stream
#pragma unroll
    for (int j = 0; j < 6; j++){
      unsigned p = pb + (unsigned)j;
      unsigned be = tf_bits(ke0, ke1, p);
      float uv = fmaxf(LO, u01_from_bits(be)*2.0f + LO);
      noise[j] = 0.01f * (1.41421356f * erfinv_xla(uv));
      if (do_dropout){
        unsigned bd = tf_bits(kd0, kd1, p);
        if (bd < 0x80000000u) dmask |= (1u << j);
      }
      if (!write_h){
        unsigned bq = tf_bits(kq0, kq1, p);
        qb[j] = (u01_from_bits(bq) - 0.5f)*delta_n;
      }
    }
  }
  // pin: forbid the compiler from sinking the RNG below the gather
  asm volatile("" :
    "+v"(noise[0]),"+v"(noise[1]),"+v"(noise[2]),"+v"(noise[3]),
    "+v"(noise[4]),"+v"(noise[5]),
    "+v"(qb[0]),"+v"(qb[1]),"+v"(qb[2]),"+v"(qb[3]),
    "+v"(qb[4]),"+v"(qb[5]),
    "+v"(dmask));

  const char* hqc = (const char*)hq_in;

  // ---- phase 1: gather 16 rows, 2 passes of 8 concurrent rows ----
#pragma unroll 1
  for (int pass = 0; pass < 2; pass++){
    int r = pass*8 + ty;
    int row = n0 + r;
    if (tx < 24){
      float4 o = make_float4(0.f, 0.f, 0.f, 0.f);
      if (row < N){
        unsigned txb = (unsigned)tx*8u;
        float dd = dsqr[row];
        unsigned lo = (unsigned)rowptr[row], hi = (unsigned)rowptr[row+1];
        uint2 sraw = *(const uint2*)(hqc + (unsigned)row*192u + txb);
        float4 hz = ntld_f4(h0p + (size_t)row*96 + tx*4);
        float2 s01 = __half22float2(*(__half2*)&sraw.x);
        float2 s23 = __half22float2(*(__half2*)&sraw.y);
        float ax = s01.x*dd, ay = s01.y*dd, az = s23.x*dd, aw = s23.y*dd;
        unsigned s = lo;
        unsigned n16 = lo + ((hi - lo) & ~15u);
        for (; s < n16; s += 16){
          int4   sa = ntld_i4(csr_src + s);
          int4   sb = ntld_i4(csr_src + s + 4);
          int4   sc = ntld_i4(csr_src + s + 8);
          int4   sd = ntld_i4(csr_src + s + 12);
          float4 wa = ntld_f4(csr_w + s);
          float4 wb = ntld_f4(csr_w + s + 4);
          float4 wc = ntld_f4(csr_w + s + 8);
          float4 wd = ntld_f4(csr_w + s + 12);
          uint2 g0 = *(const uint2*)(hqc + (unsigned)sa.x*192u + txb);
          uint2 g1 = *(const uint2*)(hqc + (unsigned)sa.y*192u + txb);
          uint2 g2 = *(const uint2*)(hqc + (unsigned)sa.z*192u + txb);
          uint2 g3 = *(const uint2*)(hqc + (unsigned)sa.w*192u + txb);
          uint2 g4 = *(const uint2*)(hqc + (unsigned)sb.x*192u + txb);
          uint2 g5 = *(const uint2*)(hqc + (unsigned)sb.y*192u + txb);
          uint2 g6 = *(const uint2*)(hqc + (unsigned)sb.z*192u + txb);
          uint2 g7 = *(const uint2*)(hqc + (unsigned)sb.w*192u + txb);
          uint2 g8 = *(const uint2*)(hqc + (unsigned)sc.x*192u + txb);
          uint2 g9 = *(const uint2*)(hqc + (unsigned)sc.y*192u + txb);
          uint2 gA = *(const uint2*)(hqc + (unsigned)sc.z*192u + txb);
          uint2 gB = *(const uint2*)(hqc + (unsigned)sc.w*192u + txb);
          uint2 gC = *(const uint2*)(hqc + (unsigned)sd.x*192u + txb);
          uint2 gD = *(const uint2*)(hqc + (unsigned)sd.y*192u + txb);
          uint2 gE = *(const uint2*)(hqc + (unsigned)sd.z*192u + txb);
          uint2 gF = *(const uint2*)(hqc + (unsigned)sd.w*192u + txb);
          GATH(g0, wa.x) GATH(g1, wa.y) GATH(g2, wa.z) GATH(g3, wa.w)
          GATH(g4, wb.x) GATH(g5, wb.y) GATH(g6, wb.z) GATH(g7, wb.w)
          GATH(g8, wc.x) GATH(g9, wc.y) GATH(gA, wc.z) GATH(gB, wc.w)
          GATH(gC, wd.x) GATH(gD, wd.y) GATH(gE, wd.z) GATH(gF, wd.w)
        }
        for (; s < hi; s += 8){
          int4   sa = ntld_i4(csr_src + s);
          int4   sb = ntld_i4(csr_src + s + 4);
          float4 wa = ntld_f4(csr_w + s);
          float4 wb = ntld_f4(csr_w + s + 4);
          uint2 g0 = *(const uint2*)(hqc + (unsigned)sa.x*192u + txb);
          uint2 g1 = *(const uint2*)(hqc + (unsigned)sa.y*192u + txb);
          uint2 g2 = *(const uint2*)(hqc + (unsigned)sa.z*192u + txb);
          uint2 g3 = *(const uint2*)(hqc + (unsigned)sa.w*192u + txb);
          uint2 g4 = *(const uint2*)(hqc + (unsigned)sb.x*192u + txb);
          uint2 g5 = *(const uint2*)(hqc + (unsigned)sb.y*192u + txb);
          uint2 g6 = *(const uint2*)(hqc + (unsigned)sb.z*192u + txb);
          uint2 g7 = *(const uint2*)(hqc + (unsigned)sb.w*192u + txb);
          GATH(g0, wa.x) GATH(g1, wa.y) GATH(g2, wa.z) GATH(g3, wa.w)
          GATH(g4, wb.x) GATH(g5, wb.y) GATH(g6, wb.z) GATH(g7, wb.w)
        }
        o.x = 0.9f*ax + 0.1f*hz.x;
        o.y = 0.9f*ay + 0.1f*hz.y;
        o.z = 0.9f*az + 0.1f*hz.z;
        o.w = 0.9f*aw + 0.1f*hz.w;
      }
      *((float4*)&ts[r*100 + tx*4]) = o;
    }
  }

  __syncthreads();   // the ONLY barrier: ts + wsh complete

  // ---- phase 2: matmul, full K=96, no further barriers ----
  float acc[6];
#pragma unroll
  for (int j = 0; j < 6; j++) acc[j] = 0.f;
#pragma unroll 4
  for (int k = 0; k < 96; k++){
    float2 w0 = *((const float2*)&wsh[k*96 + c0]);
    float2 w1 = *((const float2*)&wsh[k*96 + c0 + 2]);
    float2 w2 = *((const float2*)&wsh[k*96 + c0 + 4]);
    float xv = ts[ng*100 + k];
    acc[0] = fmaf(xv, w0.x, acc[0]);  acc[1] = fmaf(xv, w0.y, acc[1]);
    acc[2] = fmaf(xv, w1.x, acc[2]);  acc[3] = fmaf(xv, w1.y, acc[3]);
    acc[4] = fmaf(xv, w2.x, acc[4]);  acc[5] = fmaf(xv, w2.y, acc[5]);
  }

  // ---- light epilogue (RNG already in registers) ----
  if (n < N){
    float res[6];
#pragma unroll
    for (int j = 0; j < 6; j++){
      int c = c0 + j;
      float tv = ts[ng*100 + c];
      float hv = ombf*tv + betaf*acc[j];
      hv += noise[j];
      hv = fmaxf(hv, 0.0f);
      if (do_dropout)
        hv = (dmask & (1u << j)) ? hv*2.0f : 0.0f;
      if (!write_h)
        hv = floorf((hv + qb[j])*invdelta_n)*delta_n - qb[j];
      res[j] = hv;
    }
    if (write_h){
      float* dst2 = h_out + (size_t)n*96 + c0;
      ntst_f2(&dst2[0], res[0], res[1]);
      ntst_f2(&dst2[2], res[2], res[3]);
      ntst_f2(&dst2[4], res[4], res[5]);
    } else {
      __half* dst2 = hq_out + (size_t)n*96 + c0;
#pragma unroll
      for (int j2 = 0; j2 < 3; j2++){
        unsigned pk = (unsigned)__half_as_ushort(__float2half_rn(res[j2*2+0]))
                    | ((unsigned)__half_as_ushort(__float2half_rn(res[j2*2+1])) << 16);
        ntst_u1(dst2 + j2*2, pk);
      }
    }
  }
}

// ---------------- out = [h0, h] @ out_w + out_b (inputs r-order, output scattered) ----------------
__global__ __launch_bounds__(256) void k_final(
  const float* __restrict__ h0p, const float* __restrict__ hp,
  const float* __restrict__ W, const float* __restrict__ bias,
  const int* __restrict__ perm, float* __restrict__ out, int N)
{
  __shared__ float xs[64*97];
  __shared__ float wsh[96*40];
  int tid = threadIdx.x; int n0 = blockIdx.x*64;
  int cg = tid & 7, ng = tid >> 3; int c0 = cg*5;
  float acc[2][5];
#pragma unroll
  for (int i=0;i<2;i++) for (int j=0;j<5;j++) acc[i][j]=0.f;
  for (int ph=0; ph<2; ph++){
    if (ph) __syncthreads();
    const float* xsrc = ph ? hp : h0p;
    for (int q=tid; q<960; q+=256)
      ((float4*)wsh)[q] = ((const float4*)(W + ph*96*40))[q];
    for (int q=tid; q<1536; q+=256){
      int g=q*4; int r=g/96, col=g%96;
      int n=n0+r; int ns = n<N ? n : N-1;
      float4 v = ((const float4*)(xsrc + (size_t)ns*96))[col>>2];
      xs[r*97+col]=v.x; xs[r*97+col+1]=v.y; xs[r*97+col+2]=v.z; xs[r*97+col+3]=v.w;
    }
    __syncthreads();
    for (int k=0;k<96;k++){
      float wv[5];
#pragma unroll
      for (int j=0;j<5;j++) wv[j]=wsh[k*40 + c0 + j];
#pragma unroll
      for (int i=0;i<2;i++){
        float xv = xs[(ng*2+i)*97 + k];
#pragma unroll
        for (int j=0;j<5;j++) acc[i][j] = fmaf(xv, wv[j], acc[i][j]);
      }
    }
  }
#pragma unroll
  for (int i=0;i<2;i++){
    int n = n0 + ng*2 + i; if (n >= N) continue;
    int pm = perm[n];
#pragma unroll
    for (int j=0;j<5;j++)
      out[(size_t)pm*40 + c0 + j] = acc[i][j] + bias[c0 + j];
  }
}

// ---------------- host ----------------
static void tf_host(uint32_t k0, uint32_t k1, uint32_t x0, uint32_t x1,
                    uint32_t &y0, uint32_t &y1){
  uint32_t ks2 = k0 ^ k1 ^ 0x1BD11BDAu;
  x0 += k0; x1 += k1;
  auto R = [&](int r){ x0 += x1; x1 = (x1<<r)|(x1>>(32-r)); x1 ^= x0; };
  R(13);R(15);R(26);R(6);   x0 += k1;  x1 += ks2 + 1u;
  R(17);R(29);R(16);R(24);  x0 += ks2; x1 += k0 + 2u;
  R(13);R(15);R(26);R(6);   x0 += k0;  x1 += k1 + 3u;
  R(17);R(29);R(16);R(24);  x0 += k1;  x1 += ks2 + 4u;
  R(13);R(15);R(26);R(6);   x0 += ks2; x1 += k0 + 5u;
  y0 = x0; y1 = x1;
}

extern "C" void kernel_launch(void* const* d_in, const int* in_sizes, int n_in,
                              void* d_out, int out_size, void* d_ws, size_t ws_size,
                              hipStream_t stream)
{
  const float*    x       = (const float*)d_in[0];
  const unsigned* eraw    = (const unsigned*)d_in[1];
  const float*    proj_w  = (const float*)d_in[2];
  const float*    proj_b  = (const float*)d_in[3];
  const float*    conv_w  = (const float*)d_in[4];
  const float*    out_w   = (const float*)d_in[5];
  const float*    out_b   = (const float*)d_in[6];
  float* out = (float*)d_out;

  const int N = in_sizes[0] / INC;     // 50000
  const int E = in_sizes[1] / 2;       // 800000
  const size_t NH = (size_t)N * HID;
  const int NP = (N + 16) & ~15;
  const int EP = ((E + 7*N + 15) & ~15);   // padded-CSR capacity (rows padded to x8)

  float*  ws     = (float*)d_ws;
  float*  h0p    = ws;                       // NH f32 (perm order)
  float*  hbp    = h0p + NH;                 // NH f32, last-layer h (perm order)
  __half* hqA    = (__half*)(hbp + NH);      // NH fp16 (ping, perm order)
  __half* hqB    = hqA + NH;                 // NH fp16 (pong)
  float*  csr_w  = (float*)(hqB + NH);       // EP f32
  int*    csr_src= (int*)(csr_w + EP);       // EP int
  int*    rowptr = csr_src + EP;             // NP (+1 used)
  int*    perm   = rowptr + NP;
  int*    iperm  = perm + NP;
  int*    degv   = iperm + NP;
  int*    degp   = degv + NP;
  int*    cnt    = degp + NP;
  int*    cur    = cnt + NP;
  float*  diso   = (float*)(cur + NP);
  float*  dsqr   = diso + NP;
  int*    bcnt   = (int*)(dsqr + NP);
  int*    psum   = bcnt + 64;
  int*    flag   = psum + 256;
  (void)ws_size; (void)n_in; (void)out_size;

  // JAX key chain: key(42) -> per layer split(key,4)
  uint32_t kq[8][2], ke[8][2], kd[8][2];
  {
    uint32_t K0 = 0u, K1 = 42u;
    for (int k = 0; k < 8; k++){
      uint32_t y0, y1;
      tf_host(K0, K1, 0u, 0u, y0, y1); kq[k][0]=y0; kq[k][1]=y1;
      tf_host(K0, K1, 0u, 1u, y0, y1); ke[k][0]=y0; ke[k][1]=y1;
      tf_host(K0, K1, 0u, 2u, y0, y1); kd[k][0]=y0; kd[k][1]=y1;
      tf_host(K0, K1, 0u, 3u, y0, y1); K0=y0; K1=y1;
    }
  }

  const int gE  = (E + 255)/256;
  const int gN  = (N + 255)/256;
  const int gMM = (N + 63)/64;
  const int gL  = (N + ROWS-1)/ROWS;

  hipMemsetAsync(cnt, 0, (size_t)N*4, stream);
  hipMemsetAsync(bcnt, 0, 64*4, stream);
  k_detect   <<<1, 64, 0, stream>>>(eraw, flag);
  k_convcount<<<gE, 256, 0, stream>>>(eraw, flag, E, cnt);
  k_hist     <<<gN, 256, 0, stream>>>(cnt, N, bcnt);
  k_bucketoff<<<1, 64, 0, stream>>>(bcnt);
  k_perm     <<<gN, 256, 0, stream>>>(cnt, N, bcnt, perm, iperm, diso, dsqr, degv, degp);
  k_scanA    <<<gN, 256, 0, stream>>>(degp, N, psum);
  k_scanB    <<<1, 256, 0, stream>>>(psum, gN);
  k_rowptr2  <<<gN, 256, 0, stream>>>(degv, degp, psum, N, rowptr, csr_src, csr_w);
  hipMemsetAsync(cur, 0, (size_t)N*4, stream);
  k_fill     <<<gE, 256, 0, stream>>>(eraw, flag, E, rowptr, iperm, cur, diso, csr_src, csr_w);

  k_h0<<<gMM, 256, 0, stream>>>(x, proj_w, proj_b, iperm, h0p, hqA, kq[0][0], kq[0][1], N);

  for (int k = 0; k < 8; k++){
    double bd = log(0.5/(double)(k+1) + 1.0);
    float betaf = (float)bd;
    float ombf  = (float)(1.0 - bd);
    int last = (k == 7);
    float dn  = 1.0f/(float)(1 << (k+1));
    float idn = (float)(1 << (k+1));
    const __half* hin  = (k & 1) ? hqB : hqA;   // ping-pong: no read/write race
    __half*       hout = (k & 1) ? hqA : hqB;
    k_layer<<<gL, 256, 0, stream>>>(hin, h0p, dsqr, rowptr, csr_src, csr_w, perm,
      conv_w + (size_t)k*HID*HID, betaf, ombf,
      ke[k][0], ke[k][1], kd[k][0], kd[k][1],
      last?0u:kq[k+1][0], last?0u:kq[k+1][1], dn, idn,
      !last, last, hout, hbp, N);
  }

  k_final<<<gMM, 256, 0, stream>>>(h0p, hbp, out_w, out_b, perm, out, N);
}